// Round 1
// baseline (10587.941 us; speedup 1.0000x reference)
//
#include <hip/hip_runtime.h>

// Problem constants
#define B_ 256
#define L_ 196
#define C_ 768
#define K_ 2048
#define BL_ 50176  // B_*L_

// ---------------------------------------------------------------------------
// Kernel P: per-code precompute.
//  - transpose codebook -> cbT[c][k]  (coalesced inner-loop loads in kernel D)
//  - norms[k] = ||cb[k]||^2 in f64 (argmin-exact)
//  - ac[k] = relu(cb[k] . att_w_center)   (conv1d(k=3,pad=1) on length-1 seq
//    reduces to the center tap; attention value only depends on chosen code)
// One wave per code; 4 codes per 256-thread block.
// ---------------------------------------------------------------------------
__global__ __launch_bounds__(256) void precompute_kernel(
    const float* __restrict__ cb, const float* __restrict__ attw,
    float* __restrict__ cbT, double* __restrict__ norms,
    float* __restrict__ ac) {
  int wave = threadIdx.x >> 6;
  int lane = threadIdx.x & 63;
  int k = blockIdx.x * 4 + wave;
  const float* row = cb + (size_t)k * C_;
  double n = 0.0, a = 0.0;
  for (int c = lane; c < C_; c += 64) {
    float v = row[c];
    cbT[(size_t)c * K_ + k] = v;
    n = fma((double)v, (double)v, n);
    a = fma((double)v, (double)attw[c * 3 + 1], a);
  }
  // wave butterfly reduce (64 lanes)
  for (int off = 32; off > 0; off >>= 1) {
    n += __shfl_down(n, off);
    a += __shfl_down(a, off);
  }
  if (lane == 0) {
    norms[k] = n;
    ac[k] = (a > 0.0) ? (float)a : 0.0f;
  }
}

// ---------------------------------------------------------------------------
// Kernel D: argmin_k ( ||e_k||^2 - 2 x.e_k )  per token, f64-exact.
// Block: 512 threads, 32 tokens staged in LDS (fp32, 98 KB).
// Thread (code_lane = tid&255, half = tid>>8): 8 codes (code_lane + j*256)
// x 16 tokens (half*16..+16). f64 accumulate; products of f32 inputs are
// exact in f64 fma, so argmin matches an f64 reference bit-for-bit.
// ---------------------------------------------------------------------------
#define TT_ 32
__global__ __launch_bounds__(512, 2) void argmin_kernel(
    const float* __restrict__ x, const float* __restrict__ cbT,
    const double* __restrict__ norms, int* __restrict__ out_idx) {
  __shared__ float As[TT_ * C_];      // 98304 B
  __shared__ double red_v[TT_][4];
  __shared__ int red_i[TT_][4];

  int tid = threadIdx.x;
  size_t tok0 = (size_t)blockIdx.x * TT_;

  // stage 32 tokens x 768 c as float4 (6144 float4, 12 per thread)
  const float4* src = (const float4*)(x + tok0 * C_);
  float4* dst = (float4*)As;
  for (int i = tid; i < TT_ * C_ / 4; i += 512) dst[i] = src[i];
  __syncthreads();

  int code_lane = tid & 255;
  int half = tid >> 8;  // 0 or 1
  const float* Ah = As + half * 16 * C_;

  double minv[16];
  int mini[16];
#pragma unroll
  for (int t = 0; t < 16; ++t) { minv[t] = 1e300; mini[t] = 0; }

  for (int j = 0; j < 8; ++j) {
    int k = code_lane + j * 256;
    const float* wcol = cbT + k;
    double acc[16];
#pragma unroll
    for (int t = 0; t < 16; ++t) acc[t] = 0.0;
    for (int c = 0; c < C_; ++c) {
      double w = (double)wcol[(size_t)c * K_];  // coalesced across lanes
#pragma unroll
      for (int t = 0; t < 16; ++t)
        acc[t] = fma((double)Ah[t * C_ + c], w, acc[t]);  // LDS broadcast
    }
    double nk = norms[k];
#pragma unroll
    for (int t = 0; t < 16; ++t) {
      double d = fma(-2.0, acc[t], nk);
      if (d < minv[t]) { minv[t] = d; mini[t] = k; }  // strict < keeps first k
    }
  }

  // per-token wave reduce (64 code-lanes within the wave share one half)
#pragma unroll
  for (int t = 0; t < 16; ++t) {
    double v = minv[t];
    int i0 = mini[t];
    for (int off = 32; off > 0; off >>= 1) {
      double ov = __shfl_down(v, off);
      int oi = __shfl_down(i0, off);
      if (ov < v || (ov == v && oi < i0)) { v = ov; i0 = oi; }
    }
    minv[t] = v;
    mini[t] = i0;
  }
  int wave = tid >> 6;           // 0..7
  int lane = tid & 63;
  int wih = wave & 3;            // wave index within half
  if (lane == 0) {
#pragma unroll
    for (int t = 0; t < 16; ++t) {
      int tg = half * 16 + t;
      red_v[tg][wih] = minv[t];
      red_i[tg][wih] = mini[t];
    }
  }
  __syncthreads();
  if (tid < TT_) {
    double v = red_v[tid][0];
    int i0 = red_i[tid][0];
    for (int q = 1; q < 4; ++q) {
      double ov = red_v[tid][q];
      int oi = red_i[tid][q];
      if (ov < v || (ov == v && oi < i0)) { v = ov; i0 = oi; }
    }
    out_idx[tok0 + tid] = i0;
  }
}

// ---------------------------------------------------------------------------
// Kernel E: per-batch softmax over att = ac[idx[l]] (L=196) + fused output:
//   out[b,l,:] = cb[idx[b,l]] + in[b,l,:] * mask[b,l]
// Also writes the index map as float (d_out is read as one fp32 buffer).
// ---------------------------------------------------------------------------
__global__ __launch_bounds__(256) void epilogue_kernel(
    const float* __restrict__ x, const float* __restrict__ cb,
    const float* __restrict__ ac, const int* __restrict__ idx,
    float* __restrict__ out, float* __restrict__ out_idx) {
  __shared__ float att[256];
  __shared__ float red[256];
  __shared__ int ids[L_];
  int b = blockIdx.x;
  int tid = threadIdx.x;

  float a = -1e30f;
  int myid = 0;
  if (tid < L_) {
    myid = idx[b * L_ + tid];
    ids[tid] = myid;
    a = ac[myid];
  }
  att[tid] = a;
  red[tid] = a;
  __syncthreads();
  for (int s = 128; s > 0; s >>= 1) {
    if (tid < s) red[tid] = fmaxf(red[tid], red[tid + s]);
    __syncthreads();
  }
  float m = red[0];
  __syncthreads();
  float e = (tid < L_) ? expf(att[tid] - m) : 0.0f;
  red[tid] = e;
  __syncthreads();
  for (int s = 128; s > 0; s >>= 1) {
    if (tid < s) red[tid] += red[tid + s];
    __syncthreads();
  }
  float sum = red[0];
  __syncthreads();
  att[tid] = e / sum;  // mask
  __syncthreads();

  const float4* xin = (const float4*)(x + (size_t)b * L_ * C_);
  float4* o = (float4*)(out + (size_t)b * L_ * C_);
  for (int i = tid; i < L_ * (C_ / 4); i += 256) {
    int l = i / (C_ / 4);
    int c4 = i - l * (C_ / 4);
    const float4* crow = (const float4*)(cb + (size_t)ids[l] * C_);
    float4 xv = xin[i];
    float4 cv = crow[c4];
    float mk = att[l];
    float4 ov;
    ov.x = cv.x + xv.x * mk;
    ov.y = cv.y + xv.y * mk;
    ov.z = cv.z + xv.z * mk;
    ov.w = cv.w + xv.w * mk;
    o[i] = ov;
  }
  if (tid < L_) out_idx[b * L_ + tid] = (float)ids[tid];
}

// ---------------------------------------------------------------------------
extern "C" void kernel_launch(void* const* d_in, const int* in_sizes, int n_in,
                              void* d_out, int out_size, void* d_ws,
                              size_t ws_size, hipStream_t stream) {
  const float* in_feas = (const float*)d_in[0];   // [B,L,C] f32
  const float* cb = (const float*)d_in[1];        // [K,C]   f32
  const float* attw = (const float*)d_in[2];      // [1,C,3] f32

  // workspace layout
  char* ws = (char*)d_ws;
  float* cbT = (float*)ws;                                   // 6291456 B
  double* norms = (double*)(ws + 6291456);                   // 16384 B
  float* ac = (float*)(ws + 6291456 + 16384);                // 8192 B
  int* idx = (int*)(ws + 6291456 + 16384 + 8192);            // 200704 B

  float* out = (float*)d_out;                      // out_feas [B,L,C]
  float* out_idx = out + (size_t)B_ * L_ * C_;     // idx map as float [B,H,W]

  precompute_kernel<<<K_ / 4, 256, 0, stream>>>(cb, attw, cbT, norms, ac);
  argmin_kernel<<<BL_ / TT_, 512, 0, stream>>>(in_feas, cbT, norms, idx);
  epilogue_kernel<<<B_, 256, 0, stream>>>(in_feas, cb, ac, idx, out, out_idx);
}

// Round 2
// 1403.391 us; speedup vs baseline: 7.5445x; 7.5445x over previous
//
#include <hip/hip_runtime.h>

// Problem constants
#define B_ 256
#define L_ 196
#define C_ 768
#define K_ 2048
#define BL_ 50176  // B_*L_

typedef __attribute__((ext_vector_type(8))) short bf16x8;
typedef __attribute__((ext_vector_type(4))) float f32x4;

__device__ __forceinline__ unsigned short f2bf(float f) {
  unsigned u = __builtin_bit_cast(unsigned, f);
  u = u + 0x7FFFu + ((u >> 16) & 1u);  // RNE, no NaN inputs
  return (unsigned short)(u >> 16);
}

// ---------------------------------------------------------------------------
// Kernel P: per-code precompute.
//  - cb_bf16[k][c]  (row-major bf16 codebook for MFMA B-fragments)
//  - norms64[k] = ||cb[k]||^2 f64 (exact rescore), norms32[k] (approx filter)
//  - ac[k] = relu(cb[k] . att_w_center)
// ---------------------------------------------------------------------------
__global__ __launch_bounds__(256) void precompute_kernel(
    const float* __restrict__ cb, const float* __restrict__ attw,
    unsigned short* __restrict__ cbb, double* __restrict__ norms64,
    float* __restrict__ norms32, float* __restrict__ ac) {
  int wave = threadIdx.x >> 6;
  int lane = threadIdx.x & 63;
  int k = blockIdx.x * 4 + wave;
  const float* row = cb + (size_t)k * C_;
  double n = 0.0, a = 0.0;
  for (int c = lane; c < C_; c += 64) {
    float v = row[c];
    cbb[(size_t)k * C_ + c] = f2bf(v);
    n = fma((double)v, (double)v, n);
    a = fma((double)v, (double)attw[c * 3 + 1], a);
  }
  for (int off = 32; off > 0; off >>= 1) {
    n += __shfl_down(n, off);
    a += __shfl_down(a, off);
  }
  if (lane == 0) {
    norms64[k] = n;
    norms32[k] = (float)n;
    ac[k] = (a > 0.0) ? (float)a : 0.0f;
  }
}

// ---------------------------------------------------------------------------
// Kernel D: MFMA bf16 approximate distances + exact f64 rescore of top-6.
// Block: 256 thr / 4 waves, Mtile=32 tokens (LDS-resident bf16, pad +8).
// Each wave: 32 tokens x 128 codes per chunk (2 Mtiles x 8 Ntiles of
// 16x16x32 MFMA), 4 chunks cover K_=2048 codes. B-frags direct from L2.
// Approx distance key = (f32 bits of d~ & ~0x7FF) | code  (positive f32 ->
// uint order == float order; low bits tie-break toward smaller code).
// Top-3 per (wave,chunk) group via shuffle+mask, top-6 overall, f64 rescore.
// ---------------------------------------------------------------------------
#define APAD 776  // 768 + 8 bf16 padding
__global__ __launch_bounds__(256, 2) void argmin_kernel(
    const float* __restrict__ x, const float* __restrict__ cb,
    const unsigned short* __restrict__ cbb,
    const double* __restrict__ norms64, const float* __restrict__ norms32,
    int* __restrict__ out_idx) {
  __shared__ unsigned short As[32 * APAD];   // 49664 B
  __shared__ float norms_s[K_];              // 8192 B
  __shared__ unsigned int cands[32][48];     // 6144 B
  __shared__ int rcode[32][6];
  __shared__ double rd[32][6];

  int tid = threadIdx.x;
  size_t tok0 = (size_t)blockIdx.x * 32;

  for (int i = tid; i < K_; i += 256) norms_s[i] = norms32[i];

  // stage A: 32 tokens x 768 f32 -> bf16 LDS (padded rows)
  const float4* xin = (const float4*)(x + tok0 * C_);
  for (int i = tid; i < 32 * 192; i += 256) {
    int tok = i / 192;
    int c4 = i - tok * 192;
    float4 v = xin[i];
    uint2 w;
    w.x = (unsigned)f2bf(v.x) | ((unsigned)f2bf(v.y) << 16);
    w.y = (unsigned)f2bf(v.z) | ((unsigned)f2bf(v.w) << 16);
    *(uint2*)&As[tok * APAD + c4 * 4] = w;
  }
  __syncthreads();

  int wv = tid >> 6;
  int lane = tid & 63;
  int col = lane & 15;
  int quad = lane >> 4;

  const unsigned short* a0p = &As[(col)*APAD + quad * 8];
  const unsigned short* a1p = &As[(16 + col) * APAD + quad * 8];

  for (int chunk = 0; chunk < 4; ++chunk) {
    int code0 = chunk * 512 + wv * 128 + col;  // + n*16
    const unsigned short* bbase = cbb + (size_t)code0 * C_ + quad * 8;

    f32x4 acc[2][8];
#pragma unroll
    for (int m = 0; m < 2; ++m)
#pragma unroll
      for (int n = 0; n < 8; ++n) acc[m][n] = (f32x4){0.f, 0.f, 0.f, 0.f};

    // single-stage software pipeline
    bf16x8 ca0 = *(const bf16x8*)(a0p);
    bf16x8 ca1 = *(const bf16x8*)(a1p);
    bf16x8 cbf[8];
#pragma unroll
    for (int n = 0; n < 8; ++n)
      cbf[n] = *(const bf16x8*)(bbase + (size_t)n * 16 * C_);

    for (int ks = 0; ks < 24; ++ks) {
      bf16x8 na0, na1, nbf[8];
      if (ks < 23) {
        int k1 = (ks + 1) * 32;
        na0 = *(const bf16x8*)(a0p + k1);
        na1 = *(const bf16x8*)(a1p + k1);
#pragma unroll
        for (int n = 0; n < 8; ++n)
          nbf[n] = *(const bf16x8*)(bbase + (size_t)n * 16 * C_ + k1);
      }
#pragma unroll
      for (int n = 0; n < 8; ++n) {
        acc[0][n] = __builtin_amdgcn_mfma_f32_16x16x32_bf16(
            ca0, cbf[n], acc[0][n], 0, 0, 0);
        acc[1][n] = __builtin_amdgcn_mfma_f32_16x16x32_bf16(
            ca1, cbf[n], acc[1][n], 0, 0, 0);
      }
      if (ks < 23) {
        ca0 = na0;
        ca1 = na1;
#pragma unroll
        for (int n = 0; n < 8; ++n) cbf[n] = nbf[n];
      }
    }

    // epilogue: top-3 per (wave,chunk) 128-code group, per token
#pragma unroll
    for (int m = 0; m < 2; ++m) {
#pragma unroll
      for (int r = 0; r < 4; ++r) {
        unsigned keys[8];
#pragma unroll
        for (int n = 0; n < 8; ++n) {
          int code = code0 + n * 16;
          float d = fmaf(-2.0f, acc[m][n][r], norms_s[code]);
          keys[n] = (__builtin_bit_cast(unsigned, d) & 0xFFFFF800u) |
                    (unsigned)code;
        }
        unsigned win[3];
#pragma unroll
        for (int rnd = 0; rnd < 3; ++rnd) {
          unsigned mn = keys[0];
#pragma unroll
          for (int n = 1; n < 8; ++n) mn = min(mn, keys[n]);
          mn = min(mn, (unsigned)__shfl_xor((int)mn, 1));
          mn = min(mn, (unsigned)__shfl_xor((int)mn, 2));
          mn = min(mn, (unsigned)__shfl_xor((int)mn, 4));
          mn = min(mn, (unsigned)__shfl_xor((int)mn, 8));
          win[rnd] = mn;
#pragma unroll
          for (int n = 0; n < 8; ++n)
            if (keys[n] == mn) keys[n] = 0xFFFFFFFFu;
        }
        if (col == 0) {
          int token = m * 16 + quad * 4 + r;
          unsigned* cp = &cands[token][chunk * 12 + wv * 3];
          cp[0] = win[0];
          cp[1] = win[1];
          cp[2] = win[2];
        }
      }
    }
  }
  __syncthreads();

  // per-token top-6 of 48 approx candidates
  if (tid < 32) {
    unsigned best[6];
#pragma unroll
    for (int j = 0; j < 6; ++j) best[j] = 0xFFFFFFFFu;
    for (int s = 0; s < 48; ++s) {
      unsigned v = cands[tid][s];
      if (v < best[5]) {
        best[5] = v;
#pragma unroll
        for (int j = 5; j > 0; --j) {
          if (best[j] < best[j - 1]) {
            unsigned t = best[j];
            best[j] = best[j - 1];
            best[j - 1] = t;
          }
        }
      }
    }
#pragma unroll
    for (int j = 0; j < 6; ++j) rcode[tid][j] = (int)(best[j] & 0x7FFu);
  }
  __syncthreads();

  // exact f64 rescore: 192 threads, one (token, cand) each
  if (tid < 192) {
    int t = tid / 6;
    int j = tid - t * 6;
    int code = rcode[t][j];
    const float* xr = x + (tok0 + t) * (size_t)C_;
    const float* cr = cb + (size_t)code * C_;
    double s = 0.0;
    for (int c = 0; c < C_; c += 4) {
      float4 xa = *(const float4*)(xr + c);
      float4 ca = *(const float4*)(cr + c);
      s = fma((double)xa.x, (double)ca.x, s);
      s = fma((double)xa.y, (double)ca.y, s);
      s = fma((double)xa.z, (double)ca.z, s);
      s = fma((double)xa.w, (double)ca.w, s);
    }
    rd[t][j] = fma(-2.0, s, norms64[code]);
  }
  __syncthreads();

  if (tid < 32) {
    double bv = rd[tid][0];
    int bi = rcode[tid][0];
#pragma unroll
    for (int j = 1; j < 6; ++j) {
      double v = rd[tid][j];
      int i0 = rcode[tid][j];
      if (v < bv || (v == bv && i0 < bi)) {
        bv = v;
        bi = i0;
      }
    }
    out_idx[tok0 + tid] = bi;
  }
}

// ---------------------------------------------------------------------------
// Kernel E: per-batch softmax over att = ac[idx[l]] (L=196) + fused output:
//   out[b,l,:] = cb[idx[b,l]] + in[b,l,:] * mask[b,l]
// Also writes the index map as float.
// ---------------------------------------------------------------------------
__global__ __launch_bounds__(256) void epilogue_kernel(
    const float* __restrict__ x, const float* __restrict__ cb,
    const float* __restrict__ ac, const int* __restrict__ idx,
    float* __restrict__ out, float* __restrict__ out_idx) {
  __shared__ float att[256];
  __shared__ float red[256];
  __shared__ int ids[L_];
  int b = blockIdx.x;
  int tid = threadIdx.x;

  float a = -1e30f;
  int myid = 0;
  if (tid < L_) {
    myid = idx[b * L_ + tid];
    ids[tid] = myid;
    a = ac[myid];
  }
  att[tid] = a;
  red[tid] = a;
  __syncthreads();
  for (int s = 128; s > 0; s >>= 1) {
    if (tid < s) red[tid] = fmaxf(red[tid], red[tid + s]);
    __syncthreads();
  }
  float m = red[0];
  __syncthreads();
  float e = (tid < L_) ? expf(att[tid] - m) : 0.0f;
  red[tid] = e;
  __syncthreads();
  for (int s = 128; s > 0; s >>= 1) {
    if (tid < s) red[tid] += red[tid + s];
    __syncthreads();
  }
  float sum = red[0];
  __syncthreads();
  att[tid] = e / sum;  // mask
  __syncthreads();

  const float4* xin = (const float4*)(x + (size_t)b * L_ * C_);
  float4* o = (float4*)(out + (size_t)b * L_ * C_);
  for (int i = tid; i < L_ * (C_ / 4); i += 256) {
    int l = i / (C_ / 4);
    int c4 = i - l * (C_ / 4);
    const float4* crow = (const float4*)(cb + (size_t)ids[l] * C_);
    float4 xv = xin[i];
    float4 cv = crow[c4];
    float mk = att[l];
    float4 ov;
    ov.x = cv.x + xv.x * mk;
    ov.y = cv.y + xv.y * mk;
    ov.z = cv.z + xv.z * mk;
    ov.w = cv.w + xv.w * mk;
    o[i] = ov;
  }
  if (tid < L_) out_idx[b * L_ + tid] = (float)ids[tid];
}

// ---------------------------------------------------------------------------
extern "C" void kernel_launch(void* const* d_in, const int* in_sizes, int n_in,
                              void* d_out, int out_size, void* d_ws,
                              size_t ws_size, hipStream_t stream) {
  const float* in_feas = (const float*)d_in[0];   // [B,L,C] f32
  const float* cb = (const float*)d_in[1];        // [K,C]   f32
  const float* attw = (const float*)d_in[2];      // [1,C,3] f32

  // workspace layout
  char* ws = (char*)d_ws;
  unsigned short* cbb = (unsigned short*)ws;                 // 3145728 B
  double* norms64 = (double*)(ws + 3145728);                 // 16384 B
  float* norms32 = (float*)(ws + 3145728 + 16384);           // 8192 B
  float* ac = (float*)(ws + 3145728 + 16384 + 8192);         // 8192 B
  int* idx = (int*)(ws + 3145728 + 16384 + 8192 + 8192);     // 200704 B

  float* out = (float*)d_out;                      // out_feas [B,L,C]
  float* out_idx = out + (size_t)B_ * L_ * C_;     // idx map as float [B,H,W]

  precompute_kernel<<<K_ / 4, 256, 0, stream>>>(cb, attw, cbb, norms64,
                                                norms32, ac);
  argmin_kernel<<<BL_ / 32, 256, 0, stream>>>(in_feas, cb, cbb, norms64,
                                              norms32, idx);
  epilogue_kernel<<<B_, 256, 0, stream>>>(in_feas, cb, ac, idx, out, out_idx);
}

// Round 3
// 779.365 us; speedup vs baseline: 13.5853x; 1.8007x over previous
//
#include <hip/hip_runtime.h>

// Problem constants
#define B_ 256
#define L_ 196
#define C_ 768
#define K_ 2048
#define BL_ 50176  // B_*L_

typedef __attribute__((ext_vector_type(8))) short bf16x8;
typedef __attribute__((ext_vector_type(4))) float f32x4;

typedef const __attribute__((address_space(1))) void gas_void;
typedef __attribute__((address_space(3))) void las_void;

__device__ __forceinline__ unsigned short f2bf(float f) {
  unsigned u = __builtin_bit_cast(unsigned, f);
  u = u + 0x7FFFu + ((u >> 16) & 1u);  // RNE, no NaN inputs
  return (unsigned short)(u >> 16);
}

// monotone map: float bits -> unsigned with total order (handles negatives)
__device__ __forceinline__ unsigned fmono(float f) {
  unsigned u = __builtin_bit_cast(unsigned, f);
  return u ^ ((unsigned)((int)u >> 31) | 0x80000000u);
}

// ---------------------------------------------------------------------------
// Kernel P: per-code precompute: cbb bf16 [K][C], norms64/32, ac.
// ---------------------------------------------------------------------------
__global__ __launch_bounds__(256) void precompute_kernel(
    const float* __restrict__ cb, const float* __restrict__ attw,
    unsigned short* __restrict__ cbb, double* __restrict__ norms64,
    float* __restrict__ norms32, float* __restrict__ ac) {
  int wave = threadIdx.x >> 6;
  int lane = threadIdx.x & 63;
  int k = blockIdx.x * 4 + wave;
  const float* row = cb + (size_t)k * C_;
  double n = 0.0, a = 0.0;
  for (int c = lane; c < C_; c += 64) {
    float v = row[c];
    cbb[(size_t)k * C_ + c] = f2bf(v);
    n = fma((double)v, (double)v, n);
    a = fma((double)v, (double)attw[c * 3 + 1], a);
  }
  for (int off = 32; off > 0; off >>= 1) {
    n += __shfl_down(n, off);
    a += __shfl_down(a, off);
  }
  if (lane == 0) {
    norms64[k] = n;
    norms32[k] = (float)n;
    ac[k] = (a > 0.0) ? (float)a : 0.0f;
  }
}

// ---------------------------------------------------------------------------
// Kernel X: convert in_feas f32 -> bf16 xb [BL][C]. 9633792 float4 groups.
// ---------------------------------------------------------------------------
__global__ __launch_bounds__(256) void convert_kernel(
    const float* __restrict__ x, unsigned short* __restrict__ xb) {
  int i = blockIdx.x * 256 + threadIdx.x;  // exact: 37632*256 = BL_*C_/4
  float4 v = ((const float4*)x)[i];
  uint2 w;
  w.x = (unsigned)f2bf(v.x) | ((unsigned)f2bf(v.y) << 16);
  w.y = (unsigned)f2bf(v.z) | ((unsigned)f2bf(v.w) << 16);
  ((uint2*)xb)[i] = w;
}

// ---------------------------------------------------------------------------
// Phase 1: m97-style 128x128 BT-GEMM tile, BK=64, global_load_lds staging,
// XOR-swizzled LDS slots (swizzle applied to SOURCE address; LDS deposit is
// lane-contiguous as required). Per block: distances for 128 tokens x 128
// codes; epilogue reduces to top-3 per token per 64-code wave column ->
// 6 candidate keys per token per block into ws_cand[tok][96].
// ---------------------------------------------------------------------------
__global__ __launch_bounds__(256) void phase1_kernel(
    const unsigned short* __restrict__ xb,
    const unsigned short* __restrict__ cbb,
    const float* __restrict__ norms32, unsigned* __restrict__ ws_cand) {
  __shared__ unsigned short As[128 * 64];  // 16 KB, row=token, 128 B/row
  __shared__ unsigned short Bs[128 * 64];  // 16 KB, row=code
  __shared__ float norms_s[128];
  __shared__ unsigned cands_s[128][8];

  int tid = threadIdx.x;
  int mblk = blockIdx.x, nblk = blockIdx.y;
  size_t row0 = (size_t)mblk * 128;
  int code0 = nblk * 128;

  if (tid < 128) norms_s[tid] = norms32[code0 + tid];

  int w = tid >> 6, l = tid & 63;
  int wm = w >> 1, wn = w & 1;
  int col16 = l & 15, quad = l >> 4;

  f32x4 acc[4][4];
#pragma unroll
  for (int mt = 0; mt < 4; ++mt)
#pragma unroll
    for (int nt = 0; nt < 4; ++nt) acc[mt][nt] = (f32x4){0.f, 0.f, 0.f, 0.f};

  // staging: wave w covers tile rows [32w,32w+32), 4 insts x 64 lanes x 16 B.
  // inst i, lane l -> LDS chunk (row = 32w+8i+(l>>3), slotpos = l&7).
  // source slot is XOR-swizzled: slotraw = slotpos ^ (row&7) = (l&7)^(l>>3).
  int srow = 32 * w + (l >> 3);
  int sslot = (l & 7) ^ (l >> 3);
  const unsigned short* asrc = xb + (row0 + srow) * (size_t)C_ + sslot * 8;
  const unsigned short* bsrc =
      cbb + (size_t)(code0 + srow) * C_ + sslot * 8;
  char* alds = (char*)As + w * 4096;
  char* blds = (char*)Bs + w * 4096;

  for (int kt = 0; kt < 12; ++kt) {
    __syncthreads();
    int koff = kt * 64;
#pragma unroll
    for (int i = 0; i < 4; ++i) {
      __builtin_amdgcn_global_load_lds((gas_void*)(asrc + koff + i * 8 * C_),
                                       (las_void*)(alds + i * 1024), 16, 0, 0);
      __builtin_amdgcn_global_load_lds((gas_void*)(bsrc + koff + i * 8 * C_),
                                       (las_void*)(blds + i * 1024), 16, 0, 0);
    }
    __syncthreads();
#pragma unroll
    for (int ks = 0; ks < 2; ++ks) {
      int slot = (ks * 4 + quad) ^ (col16 & 7);  // row&7 == col16&7
      bf16x8 af[4], bf[4];
#pragma unroll
      for (int mt = 0; mt < 4; ++mt) {
        int row = wm * 64 + mt * 16 + col16;
        af[mt] = *(const bf16x8*)((const char*)As + row * 128 + slot * 16);
      }
#pragma unroll
      for (int nt = 0; nt < 4; ++nt) {
        int row = wn * 64 + nt * 16 + col16;
        bf[nt] = *(const bf16x8*)((const char*)Bs + row * 128 + slot * 16);
      }
#pragma unroll
      for (int mt = 0; mt < 4; ++mt)
#pragma unroll
        for (int nt = 0; nt < 4; ++nt)
          acc[mt][nt] = __builtin_amdgcn_mfma_f32_16x16x32_bf16(
              af[mt], bf[nt], acc[mt][nt], 0, 0, 0);
    }
  }

  // epilogue: top-3 per token within this wave's 64 codes
#pragma unroll
  for (int mt = 0; mt < 4; ++mt) {
#pragma unroll
    for (int r = 0; r < 4; ++r) {
      unsigned keys[4];
#pragma unroll
      for (int nt = 0; nt < 4; ++nt) {
        int codel = wn * 64 + nt * 16 + col16;
        float d = fmaf(-2.0f, acc[mt][nt][r], norms_s[codel]);
        keys[nt] = (fmono(d) & 0xFFFFF800u) | (unsigned)(code0 + codel);
      }
      unsigned win[3];
#pragma unroll
      for (int rnd = 0; rnd < 3; ++rnd) {
        unsigned mn = min(min(keys[0], keys[1]), min(keys[2], keys[3]));
        mn = min(mn, (unsigned)__shfl_xor((int)mn, 1));
        mn = min(mn, (unsigned)__shfl_xor((int)mn, 2));
        mn = min(mn, (unsigned)__shfl_xor((int)mn, 4));
        mn = min(mn, (unsigned)__shfl_xor((int)mn, 8));
        win[rnd] = mn;
#pragma unroll
        for (int nt = 0; nt < 4; ++nt)
          if (keys[nt] == mn) keys[nt] = 0xFFFFFFFFu;
      }
      if (col16 == 0) {
        int t = wm * 64 + mt * 16 + quad * 4 + r;
        cands_s[t][wn * 3 + 0] = win[0];
        cands_s[t][wn * 3 + 1] = win[1];
        cands_s[t][wn * 3 + 2] = win[2];
      }
    }
  }
  __syncthreads();
  for (int i = tid; i < 128 * 6; i += 256) {
    int t = i / 6;
    int j = i - t * 6;
    ws_cand[(row0 + t) * 96 + nblk * 6 + j] = cands_s[t][j];
  }
}

// ---------------------------------------------------------------------------
// Phase 2: per token, top-6 of 96 approx keys -> exact f64 rescore -> idx.
// ---------------------------------------------------------------------------
__global__ __launch_bounds__(256) void phase2_kernel(
    const float* __restrict__ x, const float* __restrict__ cb,
    const unsigned* __restrict__ ws_cand, const double* __restrict__ norms64,
    int* __restrict__ out_idx) {
  __shared__ unsigned cl[32][100];  // pad 96->100 (bank spread)
  __shared__ int rcode[32][6];
  __shared__ double rd[32][6];
  int tid = threadIdx.x;
  size_t tok0 = (size_t)blockIdx.x * 32;

  for (int i = tid; i < 32 * 96; i += 256) {
    int t = i / 96;
    int s = i - t * 96;
    cl[t][s] = ws_cand[tok0 * 96 + i];
  }
  __syncthreads();

  if (tid < 32) {
    unsigned best[6];
#pragma unroll
    for (int j = 0; j < 6; ++j) best[j] = 0xFFFFFFFFu;
    for (int s = 0; s < 96; ++s) {
      unsigned v = cl[tid][s];
      if (v < best[5]) {
        best[5] = v;
#pragma unroll
        for (int j = 5; j > 0; --j) {
          if (best[j] < best[j - 1]) {
            unsigned t = best[j];
            best[j] = best[j - 1];
            best[j - 1] = t;
          }
        }
      }
    }
#pragma unroll
    for (int j = 0; j < 6; ++j) rcode[tid][j] = (int)(best[j] & 0x7FFu);
  }
  __syncthreads();

  if (tid < 192) {
    int t = tid / 6;
    int j = tid - t * 6;
    int code = rcode[t][j];
    const float* xr = x + (tok0 + t) * (size_t)C_;
    const float* cr = cb + (size_t)code * C_;
    double s = 0.0;
    for (int c = 0; c < C_; c += 4) {
      float4 xa = *(const float4*)(xr + c);
      float4 ca = *(const float4*)(cr + c);
      s = fma((double)xa.x, (double)ca.x, s);
      s = fma((double)xa.y, (double)ca.y, s);
      s = fma((double)xa.z, (double)ca.z, s);
      s = fma((double)xa.w, (double)ca.w, s);
    }
    rd[t][j] = fma(-2.0, s, norms64[code]);
  }
  __syncthreads();

  if (tid < 32) {
    double bv = rd[tid][0];
    int bi = rcode[tid][0];
#pragma unroll
    for (int j = 1; j < 6; ++j) {
      double v = rd[tid][j];
      int i0 = rcode[tid][j];
      if (v < bv || (v == bv && i0 < bi)) {
        bv = v;
        bi = i0;
      }
    }
    out_idx[tok0 + tid] = bi;
  }
}

// ---------------------------------------------------------------------------
// Fallback argmin (round-2 kernel) if ws_size is too small for phase 1/2.
// ---------------------------------------------------------------------------
#define APAD 776
__global__ __launch_bounds__(256, 2) void argmin_fallback(
    const float* __restrict__ x, const float* __restrict__ cb,
    const unsigned short* __restrict__ cbb,
    const double* __restrict__ norms64, const float* __restrict__ norms32,
    int* __restrict__ out_idx) {
  __shared__ unsigned short Asf[32 * APAD];
  __shared__ float norms_s[K_];
  __shared__ unsigned int cands[32][48];
  __shared__ int rcode[32][6];
  __shared__ double rd[32][6];

  int tid = threadIdx.x;
  size_t tok0 = (size_t)blockIdx.x * 32;

  for (int i = tid; i < K_; i += 256) norms_s[i] = norms32[i];

  const float4* xin = (const float4*)(x + tok0 * C_);
  for (int i = tid; i < 32 * 192; i += 256) {
    int tok = i / 192;
    int c4 = i - tok * 192;
    float4 v = xin[i];
    uint2 w;
    w.x = (unsigned)f2bf(v.x) | ((unsigned)f2bf(v.y) << 16);
    w.y = (unsigned)f2bf(v.z) | ((unsigned)f2bf(v.w) << 16);
    *(uint2*)&Asf[tok * APAD + c4 * 4] = w;
  }
  __syncthreads();

  int wv = tid >> 6;
  int lane = tid & 63;
  int col = lane & 15;
  int quad = lane >> 4;

  const unsigned short* a0p = &Asf[(col)*APAD + quad * 8];
  const unsigned short* a1p = &Asf[(16 + col) * APAD + quad * 8];

  for (int chunk = 0; chunk < 4; ++chunk) {
    int code0 = chunk * 512 + wv * 128 + col;
    const unsigned short* bbase = cbb + (size_t)code0 * C_ + quad * 8;

    f32x4 acc[2][8];
#pragma unroll
    for (int m = 0; m < 2; ++m)
#pragma unroll
      for (int n = 0; n < 8; ++n) acc[m][n] = (f32x4){0.f, 0.f, 0.f, 0.f};

    bf16x8 ca0 = *(const bf16x8*)(a0p);
    bf16x8 ca1 = *(const bf16x8*)(a1p);
    bf16x8 cbf[8];
#pragma unroll
    for (int n = 0; n < 8; ++n)
      cbf[n] = *(const bf16x8*)(bbase + (size_t)n * 16 * C_);

    for (int ks = 0; ks < 24; ++ks) {
      bf16x8 na0, na1, nbf[8];
      if (ks < 23) {
        int k1 = (ks + 1) * 32;
        na0 = *(const bf16x8*)(a0p + k1);
        na1 = *(const bf16x8*)(a1p + k1);
#pragma unroll
        for (int n = 0; n < 8; ++n)
          nbf[n] = *(const bf16x8*)(bbase + (size_t)n * 16 * C_ + k1);
      }
#pragma unroll
      for (int n = 0; n < 8; ++n) {
        acc[0][n] = __builtin_amdgcn_mfma_f32_16x16x32_bf16(ca0, cbf[n],
                                                            acc[0][n], 0, 0, 0);
        acc[1][n] = __builtin_amdgcn_mfma_f32_16x16x32_bf16(ca1, cbf[n],
                                                            acc[1][n], 0, 0, 0);
      }
      if (ks < 23) {
        ca0 = na0;
        ca1 = na1;
#pragma unroll
        for (int n = 0; n < 8; ++n) cbf[n] = nbf[n];
      }
    }

#pragma unroll
    for (int m = 0; m < 2; ++m) {
#pragma unroll
      for (int r = 0; r < 4; ++r) {
        unsigned keys[8];
#pragma unroll
        for (int n = 0; n < 8; ++n) {
          int code = code0 + n * 16;
          float d = fmaf(-2.0f, acc[m][n][r], norms_s[code]);
          keys[n] = (fmono(d) & 0xFFFFF800u) | (unsigned)code;
        }
        unsigned win[3];
#pragma unroll
        for (int rnd = 0; rnd < 3; ++rnd) {
          unsigned mn = keys[0];
#pragma unroll
          for (int n = 1; n < 8; ++n) mn = min(mn, keys[n]);
          mn = min(mn, (unsigned)__shfl_xor((int)mn, 1));
          mn = min(mn, (unsigned)__shfl_xor((int)mn, 2));
          mn = min(mn, (unsigned)__shfl_xor((int)mn, 4));
          mn = min(mn, (unsigned)__shfl_xor((int)mn, 8));
          win[rnd] = mn;
#pragma unroll
          for (int n = 0; n < 8; ++n)
            if (keys[n] == mn) keys[n] = 0xFFFFFFFFu;
        }
        if (col == 0) {
          int token = m * 16 + quad * 4 + r;
          unsigned* cp = &cands[token][chunk * 12 + wv * 3];
          cp[0] = win[0];
          cp[1] = win[1];
          cp[2] = win[2];
        }
      }
    }
  }
  __syncthreads();

  if (tid < 32) {
    unsigned best[6];
#pragma unroll
    for (int j = 0; j < 6; ++j) best[j] = 0xFFFFFFFFu;
    for (int s = 0; s < 48; ++s) {
      unsigned v = cands[tid][s];
      if (v < best[5]) {
        best[5] = v;
#pragma unroll
        for (int j = 5; j > 0; --j) {
          if (best[j] < best[j - 1]) {
            unsigned t = best[j];
            best[j] = best[j - 1];
            best[j - 1] = t;
          }
        }
      }
    }
#pragma unroll
    for (int j = 0; j < 6; ++j) rcode[tid][j] = (int)(best[j] & 0x7FFu);
  }
  __syncthreads();

  if (tid < 192) {
    int t = tid / 6;
    int j = tid - t * 6;
    int code = rcode[t][j];
    const float* xr = x + (tok0 + t) * (size_t)C_;
    const float* cr = cb + (size_t)code * C_;
    double s = 0.0;
    for (int c = 0; c < C_; c += 4) {
      float4 xa = *(const float4*)(xr + c);
      float4 ca = *(const float4*)(cr + c);
      s = fma((double)xa.x, (double)ca.x, s);
      s = fma((double)xa.y, (double)ca.y, s);
      s = fma((double)xa.z, (double)ca.z, s);
      s = fma((double)xa.w, (double)ca.w, s);
    }
    rd[t][j] = fma(-2.0, s, norms64[code]);
  }
  __syncthreads();

  if (tid < 32) {
    double bv = rd[tid][0];
    int bi = rcode[tid][0];
#pragma unroll
    for (int j = 1; j < 6; ++j) {
      double v = rd[tid][j];
      int i0 = rcode[tid][j];
      if (v < bv || (v == bv && i0 < bi)) {
        bv = v;
        bi = i0;
      }
    }
    out_idx[tok0 + tid] = bi;
  }
}

// ---------------------------------------------------------------------------
// Kernel E: per-batch softmax over att = ac[idx[l]] + fused output.
// ---------------------------------------------------------------------------
__global__ __launch_bounds__(256) void epilogue_kernel(
    const float* __restrict__ x, const float* __restrict__ cb,
    const float* __restrict__ ac, const int* __restrict__ idx,
    float* __restrict__ out, float* __restrict__ out_idx) {
  __shared__ float att[256];
  __shared__ float red[256];
  __shared__ int ids[L_];
  int b = blockIdx.x;
  int tid = threadIdx.x;

  float a = -1e30f;
  int myid = 0;
  if (tid < L_) {
    myid = idx[b * L_ + tid];
    ids[tid] = myid;
    a = ac[myid];
  }
  att[tid] = a;
  red[tid] = a;
  __syncthreads();
  for (int s = 128; s > 0; s >>= 1) {
    if (tid < s) red[tid] = fmaxf(red[tid], red[tid + s]);
    __syncthreads();
  }
  float m = red[0];
  __syncthreads();
  float e = (tid < L_) ? expf(att[tid] - m) : 0.0f;
  red[tid] = e;
  __syncthreads();
  for (int s = 128; s > 0; s >>= 1) {
    if (tid < s) red[tid] += red[tid + s];
    __syncthreads();
  }
  float sum = red[0];
  __syncthreads();
  att[tid] = e / sum;
  __syncthreads();

  const float4* xin = (const float4*)(x + (size_t)b * L_ * C_);
  float4* o = (float4*)(out + (size_t)b * L_ * C_);
  for (int i = tid; i < L_ * (C_ / 4); i += 256) {
    int l = i / (C_ / 4);
    int c4 = i - l * (C_ / 4);
    const float4* crow = (const float4*)(cb + (size_t)ids[l] * C_);
    float4 xv = xin[i];
    float4 cv = crow[c4];
    float mk = att[l];
    float4 ov;
    ov.x = cv.x + xv.x * mk;
    ov.y = cv.y + xv.y * mk;
    ov.z = cv.z + xv.z * mk;
    ov.w = cv.w + xv.w * mk;
    o[i] = ov;
  }
  if (tid < L_) out_idx[b * L_ + tid] = (float)ids[tid];
}

// ---------------------------------------------------------------------------
extern "C" void kernel_launch(void* const* d_in, const int* in_sizes, int n_in,
                              void* d_out, int out_size, void* d_ws,
                              size_t ws_size, hipStream_t stream) {
  const float* in_feas = (const float*)d_in[0];   // [B,L,C] f32
  const float* cb = (const float*)d_in[1];        // [K,C]   f32
  const float* attw = (const float*)d_in[2];      // [1,C,3] f32

  // workspace layout
  char* ws = (char*)d_ws;
  size_t off = 0;
  unsigned short* cbb = (unsigned short*)(ws + off); off += 3145728;
  double* norms64 = (double*)(ws + off);           off += 16384;
  float* norms32 = (float*)(ws + off);             off += 8192;
  float* ac = (float*)(ws + off);                  off += 8192;
  int* idx = (int*)(ws + off);                     off += 200704;
  size_t base = off;                                // 3,379,200
  unsigned short* xb = (unsigned short*)(ws + off); off += (size_t)BL_ * C_ * 2;
  unsigned* ws_cand = (unsigned*)(ws + off);        off += (size_t)BL_ * 96 * 4;
  size_t need_full = off;                           // ~99.7 MB

  float* out = (float*)d_out;                      // out_feas [B,L,C]
  float* out_idx = out + (size_t)B_ * L_ * C_;     // idx map as float [B,H,W]

  precompute_kernel<<<K_ / 4, 256, 0, stream>>>(cb, attw, cbb, norms64,
                                                norms32, ac);
  if (ws_size >= need_full) {
    convert_kernel<<<BL_ * C_ / 4 / 256, 256, 0, stream>>>(in_feas, xb);
    dim3 g1(BL_ / 128, K_ / 128);
    phase1_kernel<<<g1, 256, 0, stream>>>(xb, cbb, norms32, ws_cand);
    phase2_kernel<<<BL_ / 32, 256, 0, stream>>>(in_feas, cb, ws_cand, norms64,
                                                idx);
  } else {
    argmin_fallback<<<BL_ / 32, 256, 0, stream>>>(in_feas, cb, cbb, norms64,
                                                  norms32, idx);
  }
  epilogue_kernel<<<B_, 256, 0, stream>>>(in_feas, cb, ac, idx, out, out_idx);
  (void)base;
}